// Round 5
// baseline (221.530 us; speedup 1.0000x reference)
//
#include <hip/hip_runtime.h>

// ---------------------------------------------------------------------------
// Attention_25151328485403 — f16 MFMA path, round 5
//   g1 :  qkv_h = x_h @ Wqkv^T   (mfma 16x16x32 f16, 128x128, global_load_lds)
//   vt :  V part of qkv_h transposed to [bh][64][2048]
//   at :  flash attn: S^T = K Q^T, 32 q/wave (K/V frag reuse), double-buffered
//         K/V staging w/ single barrier/tile, no running max, p = km*2^s
//   g2 :  out = aout_h @ Wout^T  (fp32 output)
// ---------------------------------------------------------------------------

typedef _Float16 half_t;
typedef __attribute__((ext_vector_type(8))) _Float16 half8;
typedef __attribute__((ext_vector_type(4))) _Float16 half4;
typedef __attribute__((ext_vector_type(4))) float floatx4;

#define SEQ 2048
#define DIM 1024
#define INNER 1024
#define NH 16
#define DH 64
#define BROWS 4096

__device__ inline void async16(const half_t* g, half_t* l) {
    __builtin_amdgcn_global_load_lds(
        (const __attribute__((address_space(1))) void*)g,
        (__attribute__((address_space(3))) void*)l, 16, 0, 0);
}

// ------------------------------ converts -----------------------------------
__global__ __launch_bounds__(256) void cvt_f32_f16(const float* __restrict__ in,
                                                   half_t* __restrict__ out) {
    int i = (blockIdx.x * 256 + threadIdx.x) * 8;
    float4 v0 = *(const float4*)(in + i);
    float4 v1 = *(const float4*)(in + i + 4);
    half_t h[8];
    h[0] = (half_t)v0.x; h[1] = (half_t)v0.y; h[2] = (half_t)v0.z; h[3] = (half_t)v0.w;
    h[4] = (half_t)v1.x; h[5] = (half_t)v1.y; h[6] = (half_t)v1.z; h[7] = (half_t)v1.w;
    *(half8*)(out + i) = *(half8*)h;
}

// in f32 [R][C] -> out f16 [C][R]; rows [0,scaleRows) of OUTPUT scaled
__global__ __launch_bounds__(256) void cvt_w_t(const float* __restrict__ in,
                                               half_t* __restrict__ out,
                                               int R, int C, int scaleRows, float scale) {
    __shared__ float tile[32][33];
    const int c0 = blockIdx.x * 32;
    const int r0 = blockIdx.y * 32;
    const int tx = threadIdx.x & 31, ty = threadIdx.x >> 5;
#pragma unroll
    for (int i = 0; i < 32; i += 8)
        tile[ty + i][tx] = in[(size_t)(r0 + ty + i) * C + c0 + tx];
    __syncthreads();
#pragma unroll
    for (int i = 0; i < 32; i += 8) {
        int oc = c0 + ty + i;
        float s = (oc < scaleRows) ? scale : 1.0f;
        out[(size_t)oc * R + r0 + tx] = (half_t)(tile[tx][ty + i] * s);
    }
}

// V part of qkv_h [4096][3072] -> vt [32 bh][64 d][2048 seq]
__global__ __launch_bounds__(256) void vtrans(const half_t* __restrict__ qkv,
                                              half_t* __restrict__ vt) {
    const int tid = threadIdx.x;
    const int d = tid & 63;
    const int wv = tid >> 6;
    const int bh = blockIdx.y;
    const int b = bh >> 4, h = bh & 15;
    const int s0 = blockIdx.x * 32 + wv * 8;
    const half_t* src = qkv + (size_t)(b * SEQ + s0) * 3072 + 2 * INNER + h * DH + d;
    half_t v[8];
#pragma unroll
    for (int j = 0; j < 8; ++j) v[j] = src[(size_t)j * 3072];   // coalesced 128B/wave
    *(half8*)(vt + ((size_t)bh * DH + d) * SEQ + s0) = *(half8*)v;
}

// ------------------------------ mfma GEMM ----------------------------------
#define GBM 128
#define GBN 128
#define GBK 64

template <int OUTF16>
__global__ __launch_bounds__(256) void gemm_f16_bt(const half_t* __restrict__ A,
                                                   const half_t* __restrict__ B,
                                                   void* __restrict__ Cout,
                                                   int M, int N, int K) {
    __shared__ half_t As[GBM * GBK];
    __shared__ half_t Bs[GBN * GBK];
    const int tid = threadIdx.x;
    const int wave = tid >> 6;
    const int lane = tid & 63;
    const int l15 = lane & 15;
    const int quad = lane >> 4;
    const int m0 = blockIdx.y * GBM;
    const int n0 = blockIdx.x * GBN;
    const int wm = (wave & 1) * 64;
    const int wn = (wave >> 1) * 64;

    floatx4 acc[4][4];
#pragma unroll
    for (int i = 0; i < 4; ++i)
#pragma unroll
        for (int j = 0; j < 4; ++j) acc[i][j] = (floatx4){0.f, 0.f, 0.f, 0.f};

    for (int k0 = 0; k0 < K; k0 += GBK) {
        __syncthreads();
#pragma unroll
        for (int i = 0; i < 4; ++i) {
            int chunk = i * 256 + tid;
            int row = chunk >> 3, c = chunk & 7;
            int gc = c ^ (row & 7);
            async16(A + (size_t)(m0 + row) * K + k0 + gc * 8, As + chunk * 8);
        }
#pragma unroll
        for (int i = 0; i < 4; ++i) {
            int chunk = i * 256 + tid;
            int row = chunk >> 3, c = chunk & 7;
            int gc = c ^ (row & 7);
            async16(B + (size_t)(n0 + row) * K + k0 + gc * 8, Bs + chunk * 8);
        }
        __syncthreads();
#pragma unroll
        for (int ks = 0; ks < 2; ++ks) {
            const int g = ks * 4 + quad;
            half8 af[4], bf[4];
#pragma unroll
            for (int i = 0; i < 4; ++i) {
                int m = wm + i * 16 + l15;
                af[i] = *(const half8*)(As + m * GBK + (g ^ (m & 7)) * 8);
            }
#pragma unroll
            for (int j = 0; j < 4; ++j) {
                int n = wn + j * 16 + l15;
                bf[j] = *(const half8*)(Bs + n * GBK + (g ^ (n & 7)) * 8);
            }
#pragma unroll
            for (int i = 0; i < 4; ++i)
#pragma unroll
                for (int j = 0; j < 4; ++j)
                    acc[i][j] = __builtin_amdgcn_mfma_f32_16x16x32_f16(af[i], bf[j],
                                                                       acc[i][j], 0, 0, 0);
        }
    }

#pragma unroll
    for (int i = 0; i < 4; ++i)
#pragma unroll
        for (int j = 0; j < 4; ++j)
#pragma unroll
            for (int r = 0; r < 4; ++r) {
                size_t row = m0 + wm + i * 16 + quad * 4 + r;
                size_t col = n0 + wn + j * 16 + l15;
                if (OUTF16)
                    ((half_t*)Cout)[row * N + col] = (half_t)acc[i][j][r];
                else
                    ((float*)Cout)[row * N + col] = acc[i][j][r];
            }
}

// ------------------------------ attention ----------------------------------
// 256 thr = 4 waves; 128 queries/block (32/wave); K-tiles of 64, double-buffered.
// S^T = K·Q^T; lane's scores share queries q0 = l15, q1 = 16+l15 (K/V frags
// reused across both halves -> half the LDS traffic per query).
__global__ __launch_bounds__(256) void attn_mfma(const half_t* __restrict__ qkv,
                                                 const half_t* __restrict__ vt,
                                                 const float* __restrict__ mask,
                                                 half_t* __restrict__ aout) {
    __shared__ half_t Ks[2][64 * 64];     // [key][d], chunks xor-swizzled
    __shared__ half_t Vs[2][64 * 64];     // [d][key], chunks xor-swizzled
    __shared__ half_t Ps[4][32 * 64];     // per-wave [q][key], chunks xor-swizzled

    const int tid = threadIdx.x;
    const int wave = tid >> 6;
    const int lane = tid & 63;
    const int l15 = lane & 15;
    const int quad = lane >> 4;
    const int sw = l15 & 7;               // xor swizzle key for rows ≡ l15 (mod 8)
    const int bh = blockIdx.y;
    const int b = bh >> 4, h = bh & 15;
    const int qi0 = blockIdx.x * 128;

    // Q fragments direct from global (log2e*0.125 folded into W_qkv q-cols)
    const half_t* qrow0 = qkv + (size_t)(b * SEQ + qi0 + wave * 32 + l15) * 3072 + h * DH;
    const half_t* qrow1 = qrow0 + (size_t)16 * 3072;
    half8 qf[2][2];
    qf[0][0] = *(const half8*)(qrow0 + quad * 8);
    qf[0][1] = *(const half8*)(qrow0 + 32 + quad * 8);
    qf[1][0] = *(const half8*)(qrow1 + quad * 8);
    qf[1][1] = *(const half8*)(qrow1 + 32 + quad * 8);
    float qm[2];
    qm[0] = mask[b * SEQ + qi0 + wave * 32 + l15];
    qm[1] = mask[b * SEQ + qi0 + wave * 32 + 16 + l15];

    const half_t* kbase0 = qkv + (size_t)b * SEQ * 3072 + INNER + h * DH;
    const half_t* vtb = vt + (size_t)bh * DH * SEQ;
    const float* mbase = mask + b * SEQ;
    half_t* Psw = &Ps[wave][0];

    floatx4 accO[2][4];
#pragma unroll
    for (int hh = 0; hh < 2; ++hh)
#pragma unroll
        for (int nt = 0; nt < 4; ++nt) accO[hh][nt] = (floatx4){0.f, 0.f, 0.f, 0.f};
    float l_i[2] = {0.f, 0.f};

    auto stage = [&](int kt, int buf) {
        const int kj0 = kt * 64;
#pragma unroll
        for (int i = 0; i < 2; ++i) {
            int chunk = i * 256 + tid;
            int row = chunk >> 3, c = chunk & 7;
            int gc = c ^ (row & 7);
            async16(kbase0 + (size_t)(kj0 + row) * 3072 + gc * 8, Ks[buf] + chunk * 8);
        }
#pragma unroll
        for (int i = 0; i < 2; ++i) {
            int chunk = i * 256 + tid;
            int row = chunk >> 3, c = chunk & 7;
            int gc = c ^ (row & 7);
            async16(vtb + (size_t)row * SEQ + kj0 + gc * 8, Vs[buf] + chunk * 8);
        }
    };

    stage(0, 0);

    for (int kt = 0; kt < SEQ / 64; ++kt) {
        const int buf = kt & 1;
        const int kj0 = kt * 64;
        __syncthreads();                  // buf ready (vmcnt drain); buf^1 free
        if (kt + 1 < SEQ / 64) stage(kt + 1, buf ^ 1);

        // key masks straight from global (L1-resident, quad-uniform broadcast)
        float4 kmv[4];
#pragma unroll
        for (int mt = 0; mt < 4; ++mt)
            kmv[mt] = *(const float4*)(mbase + kj0 + mt * 16 + quad * 4);

        // ---- S^T = K Q^T : rows = keys (mt*16+quad*4+r), cols = q (l15) ----
        floatx4 accS[2][4];
#pragma unroll
        for (int hh = 0; hh < 2; ++hh)
#pragma unroll
            for (int mt = 0; mt < 4; ++mt) accS[hh][mt] = (floatx4){0.f, 0.f, 0.f, 0.f};
#pragma unroll
        for (int ks = 0; ks < 2; ++ks) {
#pragma unroll
            for (int mt = 0; mt < 4; ++mt) {
                half8 af = *(const half8*)(Ks[buf] + (mt * 16 + l15) * 64 +
                                           ((ks * 4 + quad) ^ sw) * 8);
                accS[0][mt] = __builtin_amdgcn_mfma_f32_16x16x32_f16(af, qf[0][ks],
                                                                     accS[0][mt], 0, 0, 0);
                accS[1][mt] = __builtin_amdgcn_mfma_f32_16x16x32_f16(af, qf[1][ks],
                                                                     accS[1][mt], 0, 0, 0);
            }
        }

        // ---- p = km * 2^s (exact 0 when masked); deferred l reduction ----
#pragma unroll
        for (int hh = 0; hh < 2; ++hh)
#pragma unroll
            for (int mt = 0; mt < 4; ++mt) {
                float kmr[4] = {kmv[mt].x, kmv[mt].y, kmv[mt].z, kmv[mt].w};
                half4 p4;
#pragma unroll
                for (int r = 0; r < 4; ++r) {
                    float p = kmr[r] * __builtin_amdgcn_exp2f(accS[hh][mt][r]);
                    l_i[hh] += p;
                    p4[r] = (half_t)p;
                }
                int cw = mt * 2 + (quad >> 1);
                *(half4*)(Psw + (hh * 16 + l15) * 64 +
                          ((cw ^ sw) * 8 + (quad & 1) * 4)) = p4;
            }

        // ---- O += P V  (per-wave P: same-wave lgkmcnt ordering suffices) ----
#pragma unroll
        for (int ks2 = 0; ks2 < 2; ++ks2) {
            const int ko = ((ks2 * 4 + quad) ^ sw) * 8;
            half8 pf0 = *(const half8*)(Psw + l15 * 64 + ko);
            half8 pf1 = *(const half8*)(Psw + (16 + l15) * 64 + ko);
#pragma unroll
            for (int nt = 0; nt < 4; ++nt) {
                half8 vf = *(const half8*)(Vs[buf] + (nt * 16 + l15) * 64 + ko);
                accO[0][nt] = __builtin_amdgcn_mfma_f32_16x16x32_f16(pf0, vf,
                                                                    accO[0][nt], 0, 0, 0);
                accO[1][nt] = __builtin_amdgcn_mfma_f32_16x16x32_f16(pf1, vf,
                                                                    accO[1][nt], 0, 0, 0);
            }
        }
    }

    // final l reduction across quads (disjoint key subsets per quad)
#pragma unroll
    for (int hh = 0; hh < 2; ++hh) {
        l_i[hh] += __shfl_xor(l_i[hh], 16, 64);
        l_i[hh] += __shfl_xor(l_i[hh], 32, 64);
    }
    float linv[2];
#pragma unroll
    for (int hh = 0; hh < 2; ++hh)
        linv[hh] = (qm[hh] > 0.5f && l_i[hh] > 0.f) ? 1.0f / l_i[hh] : 0.f;
#pragma unroll
    for (int hh = 0; hh < 2; ++hh) {
        float inv[4];
#pragma unroll
        for (int r = 0; r < 4; ++r) inv[r] = __shfl(linv[hh], quad * 4 + r, 64);
#pragma unroll
        for (int nt = 0; nt < 4; ++nt)
#pragma unroll
            for (int r = 0; r < 4; ++r) {
                size_t row = (size_t)(b * SEQ + qi0 + wave * 32 + hh * 16 + quad * 4 + r);
                aout[row * INNER + h * DH + nt * 16 + l15] =
                    (half_t)(accO[hh][nt][r] * inv[r]);
            }
    }
}

// ------------------------------- launch ------------------------------------
extern "C" void kernel_launch(void* const* d_in, const int* in_sizes, int n_in,
                              void* d_out, int out_size, void* d_ws, size_t ws_size,
                              hipStream_t stream) {
    const float* x    = (const float*)d_in[0];
    const float* mask = (const float*)d_in[1];
    const float* Wqkv = (const float*)d_in[2];   // [1024][3072]
    const float* Wout = (const float*)d_in[3];   // [1024][1024]
    float* out = (float*)d_out;

    half_t* x_h    = (half_t*)d_ws;                       // 4  Mi halves
    half_t* Wqkv_t = x_h + (size_t)4 * 1024 * 1024;       // 3  Mi  [3072][1024]
    half_t* Wout_t = Wqkv_t + (size_t)3 * 1024 * 1024;    // 1  Mi  [1024][1024]
    half_t* qkv_h  = Wout_t + (size_t)1024 * 1024;        // 12 Mi  [4096][3072]
    half_t* aout_h = qkv_h + (size_t)12 * 1024 * 1024;    // 4  Mi  [4096][1024]
    half_t* vt     = aout_h + (size_t)4 * 1024 * 1024;    // 4  Mi  [32][64][2048]

    cvt_f32_f16<<<(BROWS * DIM) / (256 * 8), 256, 0, stream>>>(x, x_h);
    // q columns pre-scaled by 0.125 * log2(e) so scores are in log2 domain
    cvt_w_t<<<dim3(3 * INNER / 32, DIM / 32), 256, 0, stream>>>(
        Wqkv, Wqkv_t, DIM, 3 * INNER, INNER, 0.1803368801111f);
    cvt_w_t<<<dim3(DIM / 32, INNER / 32), 256, 0, stream>>>(
        Wout, Wout_t, INNER, DIM, 0, 1.0f);

    gemm_f16_bt<1><<<dim3(3 * INNER / GBN, BROWS / GBM), 256, 0, stream>>>(
        x_h, Wqkv_t, qkv_h, BROWS, 3 * INNER, DIM);

    vtrans<<<dim3(SEQ / 32, 2 * NH), 256, 0, stream>>>(qkv_h, vt);

    attn_mfma<<<dim3(SEQ / 128, 2 * NH), 256, 0, stream>>>(qkv_h, vt, mask, aout_h);

    gemm_f16_bt<0><<<dim3(DIM / GBN, BROWS / GBM), 256, 0, stream>>>(
        aout_h, Wout_t, out, BROWS, DIM, INNER);
}

// Round 6
// 206.169 us; speedup vs baseline: 1.0745x; 1.0745x over previous
//
#include <hip/hip_runtime.h>

// ---------------------------------------------------------------------------
// Attention_25151328485403 — f16 MFMA path, round 6
//   prep: fused converts (x->f16; W_qkv -> f16 [N][K] q-cols pre-scaled by
//         0.125*log2e; W_out -> f16 [N][K])
//   g1 :  qkv_h = x_h @ Wqkv^T   (mfma 16x16x32 f16, 128x128, global_load_lds)
//   vt :  V part of qkv_h transposed to [bh][64][2048]
//   at :  flash attn: S^T = K Q^T, 16 q/wave, 64 q/block (1024 blocks = 4/CU),
//         double-buffered K/V staging, ONE barrier/tile, no running max,
//         p = km * 2^s, deferred l-reduce
//   g2 :  out = aout_h @ Wout^T  (fp32 output)
// Round-5 lesson: 32 q/wave halves LDS traffic but shrinks grid to 2 blk/CU —
// occupancy loss beats LDS win. Keep grid at 1024 blocks.
// ---------------------------------------------------------------------------

typedef _Float16 half_t;
typedef __attribute__((ext_vector_type(8))) _Float16 half8;
typedef __attribute__((ext_vector_type(4))) _Float16 half4;
typedef __attribute__((ext_vector_type(4))) float floatx4;

#define SEQ 2048
#define DIM 1024
#define INNER 1024
#define NH 16
#define DH 64
#define BROWS 4096

__device__ inline void async16(const half_t* g, half_t* l) {
    __builtin_amdgcn_global_load_lds(
        (const __attribute__((address_space(1))) void*)g,
        (__attribute__((address_space(3))) void*)l, 16, 0, 0);
}

// ------------------------- fused prep (all converts) -----------------------
// blocks [0,2048):    x f32 -> f16 (2048 * 256 * 8 elements)
// blocks [2048,5120): W_qkv [1024][3072] -> Wqkv_t f16 [3072][1024] (32x32 tiles)
// blocks [5120,6144): W_out [1024][1024] -> Wout_t f16 [1024][1024]^T
__global__ __launch_bounds__(256) void prep(const float* __restrict__ x,
                                            const float* __restrict__ Wqkv,
                                            const float* __restrict__ Wout,
                                            half_t* __restrict__ x_h,
                                            half_t* __restrict__ Wqkv_t,
                                            half_t* __restrict__ Wout_t) {
    __shared__ float tile[32][33];
    const int bid = blockIdx.x;
    const int tid = threadIdx.x;

    if (bid < 2048) {
        int i = (bid * 256 + tid) * 8;
        float4 v0 = *(const float4*)(x + i);
        float4 v1 = *(const float4*)(x + i + 4);
        half_t h[8];
        h[0] = (half_t)v0.x; h[1] = (half_t)v0.y; h[2] = (half_t)v0.z; h[3] = (half_t)v0.w;
        h[4] = (half_t)v1.x; h[5] = (half_t)v1.y; h[6] = (half_t)v1.z; h[7] = (half_t)v1.w;
        *(half8*)(x_h + i) = *(half8*)h;
        return;
    }

    const float* in;
    half_t* out;
    int R, C, scaleRows, c0, r0;
    float scale;
    if (bid < 5120) {
        int idx = bid - 2048;                 // W_qkv: grid (96 x 32)
        in = Wqkv; out = Wqkv_t; R = DIM; C = 3 * INNER;
        scaleRows = INNER; scale = 0.1803368801111f;   // 0.125 * log2(e)
        c0 = (idx % 96) * 32; r0 = (idx / 96) * 32;
    } else {
        int idx = bid - 5120;                 // W_out: grid (32 x 32)
        in = Wout; out = Wout_t; R = INNER; C = DIM;
        scaleRows = 0; scale = 1.0f;
        c0 = (idx % 32) * 32; r0 = (idx / 32) * 32;
    }
    const int tx = tid & 31, ty = tid >> 5;
#pragma unroll
    for (int i = 0; i < 32; i += 8)
        tile[ty + i][tx] = in[(size_t)(r0 + ty + i) * C + c0 + tx];
    __syncthreads();
#pragma unroll
    for (int i = 0; i < 32; i += 8) {
        int oc = c0 + ty + i;
        float s = (oc < scaleRows) ? scale : 1.0f;
        out[(size_t)oc * R + r0 + tx] = (half_t)(tile[tx][ty + i] * s);
    }
}

// V part of qkv_h [4096][3072] -> vt [32 bh][64 d][2048 seq]
__global__ __launch_bounds__(256) void vtrans(const half_t* __restrict__ qkv,
                                              half_t* __restrict__ vt) {
    const int tid = threadIdx.x;
    const int d = tid & 63;
    const int wv = tid >> 6;
    const int bh = blockIdx.y;
    const int b = bh >> 4, h = bh & 15;
    const int s0 = blockIdx.x * 32 + wv * 8;
    const half_t* src = qkv + (size_t)(b * SEQ + s0) * 3072 + 2 * INNER + h * DH + d;
    half_t v[8];
#pragma unroll
    for (int j = 0; j < 8; ++j) v[j] = src[(size_t)j * 3072];   // coalesced 128B/wave
    *(half8*)(vt + ((size_t)bh * DH + d) * SEQ + s0) = *(half8*)v;
}

// ------------------------------ mfma GEMM ----------------------------------
#define GBM 128
#define GBN 128
#define GBK 64

template <int OUTF16>
__global__ __launch_bounds__(256) void gemm_f16_bt(const half_t* __restrict__ A,
                                                   const half_t* __restrict__ B,
                                                   void* __restrict__ Cout,
                                                   int M, int N, int K) {
    __shared__ half_t As[GBM * GBK];
    __shared__ half_t Bs[GBN * GBK];
    const int tid = threadIdx.x;
    const int wave = tid >> 6;
    const int lane = tid & 63;
    const int l15 = lane & 15;
    const int quad = lane >> 4;
    const int m0 = blockIdx.y * GBM;
    const int n0 = blockIdx.x * GBN;
    const int wm = (wave & 1) * 64;
    const int wn = (wave >> 1) * 64;

    floatx4 acc[4][4];
#pragma unroll
    for (int i = 0; i < 4; ++i)
#pragma unroll
        for (int j = 0; j < 4; ++j) acc[i][j] = (floatx4){0.f, 0.f, 0.f, 0.f};

    for (int k0 = 0; k0 < K; k0 += GBK) {
        __syncthreads();
#pragma unroll
        for (int i = 0; i < 4; ++i) {
            int chunk = i * 256 + tid;
            int row = chunk >> 3, c = chunk & 7;
            int gc = c ^ (row & 7);
            async16(A + (size_t)(m0 + row) * K + k0 + gc * 8, As + chunk * 8);
        }
#pragma unroll
        for (int i = 0; i < 4; ++i) {
            int chunk = i * 256 + tid;
            int row = chunk >> 3, c = chunk & 7;
            int gc = c ^ (row & 7);
            async16(B + (size_t)(n0 + row) * K + k0 + gc * 8, Bs + chunk * 8);
        }
        __syncthreads();
#pragma unroll
        for (int ks = 0; ks < 2; ++ks) {
            const int g = ks * 4 + quad;
            half8 af[4], bf[4];
#pragma unroll
            for (int i = 0; i < 4; ++i) {
                int m = wm + i * 16 + l15;
                af[i] = *(const half8*)(As + m * GBK + (g ^ (m & 7)) * 8);
            }
#pragma unroll
            for (int j = 0; j < 4; ++j) {
                int n = wn + j * 16 + l15;
                bf[j] = *(const half8*)(Bs + n * GBK + (g ^ (n & 7)) * 8);
            }
#pragma unroll
            for (int i = 0; i < 4; ++i)
#pragma unroll
                for (int j = 0; j < 4; ++j)
                    acc[i][j] = __builtin_amdgcn_mfma_f32_16x16x32_f16(af[i], bf[j],
                                                                       acc[i][j], 0, 0, 0);
        }
    }

#pragma unroll
    for (int i = 0; i < 4; ++i)
#pragma unroll
        for (int j = 0; j < 4; ++j)
#pragma unroll
            for (int r = 0; r < 4; ++r) {
                size_t row = m0 + wm + i * 16 + quad * 4 + r;
                size_t col = n0 + wn + j * 16 + l15;
                if (OUTF16)
                    ((half_t*)Cout)[row * N + col] = (half_t)acc[i][j][r];
                else
                    ((float*)Cout)[row * N + col] = acc[i][j][r];
            }
}

// ------------------------------ attention ----------------------------------
// 256 thr = 4 waves; 64 queries/block (16/wave); K-tiles of 64, double-buffered
// K/V with ONE barrier per tile. S^T = K·Q^T (lane's 16 scores share q = l15).
// No running max: scores sd~1, fp32 exp2 + half-P have >10 sigma headroom.
__global__ __launch_bounds__(256) void attn_mfma(const half_t* __restrict__ qkv,
                                                 const half_t* __restrict__ vt,
                                                 const float* __restrict__ mask,
                                                 half_t* __restrict__ aout) {
    __shared__ half_t Ks[2][64 * 64];     // [key][d], chunks xor-swizzled
    __shared__ half_t Vs[2][64 * 64];     // [d][key], chunks xor-swizzled
    __shared__ half_t Ps[4][16 * 64];     // per-wave [q][key], chunks xor-swizzled

    const int tid = threadIdx.x;
    const int wave = tid >> 6;
    const int lane = tid & 63;
    const int l15 = lane & 15;
    const int quad = lane >> 4;
    const int sw = l15 & 7;               // xor swizzle key for rows ≡ l15 (mod 8)
    const int bh = blockIdx.y;
    const int b = bh >> 4, h = bh & 15;
    const int qi0 = blockIdx.x * 64;

    // Q fragments direct from global (log2e*0.125 folded into W_qkv q-cols)
    const half_t* qrow = qkv + (size_t)(b * SEQ + qi0 + wave * 16 + l15) * 3072 + h * DH;
    half8 qf[2];
    qf[0] = *(const half8*)(qrow + quad * 8);
    qf[1] = *(const half8*)(qrow + 32 + quad * 8);
    const float qm = mask[b * SEQ + qi0 + wave * 16 + l15];

    const half_t* kbase0 = qkv + (size_t)b * SEQ * 3072 + INNER + h * DH;
    const half_t* vtb = vt + (size_t)bh * DH * SEQ;
    const float* mbase = mask + b * SEQ;
    half_t* Psw = &Ps[wave][0];

    floatx4 accO[4];
#pragma unroll
    for (int nt = 0; nt < 4; ++nt) accO[nt] = (floatx4){0.f, 0.f, 0.f, 0.f};
    float l_i = 0.f;    // per-lane partial: keys {mt*16+quad*4+r}, q = l15

    auto stage = [&](int kt, int buf) {
        const int kj0 = kt * 64;
#pragma unroll
        for (int i = 0; i < 2; ++i) {
            int chunk = i * 256 + tid;
            int row = chunk >> 3, c = chunk & 7;
            int gc = c ^ (row & 7);
            async16(kbase0 + (size_t)(kj0 + row) * 3072 + gc * 8, Ks[buf] + chunk * 8);
        }
#pragma unroll
        for (int i = 0; i < 2; ++i) {
            int chunk = i * 256 + tid;
            int row = chunk >> 3, c = chunk & 7;
            int gc = c ^ (row & 7);
            async16(vtb + (size_t)row * SEQ + kj0 + gc * 8, Vs[buf] + chunk * 8);
        }
    };

    stage(0, 0);

    for (int kt = 0; kt < SEQ / 64; ++kt) {
        const int buf = kt & 1;
        const int kj0 = kt * 64;
        __syncthreads();                  // buf staged (vmcnt drained); buf^1 free
        if (kt + 1 < SEQ / 64) stage(kt + 1, buf ^ 1);   // lands during this tile

        // key masks straight from global (L1-resident, quad-uniform broadcast)
        float4 kmv[4];
#pragma unroll
        for (int mt = 0; mt < 4; ++mt)
            kmv[mt] = *(const float4*)(mbase + kj0 + mt * 16 + quad * 4);

        // ---- S^T = K Q^T : rows = keys (mt*16+quad*4+r), cols = q (l15) ----
        floatx4 accS[4];
#pragma unroll
        for (int mt = 0; mt < 4; ++mt) accS[mt] = (floatx4){0.f, 0.f, 0.f, 0.f};
#pragma unroll
        for (int ks = 0; ks < 2; ++ks) {
#pragma unroll
            for (int mt = 0; mt < 4; ++mt) {
                half8 af = *(const half8*)(Ks[buf] + (mt * 16 + l15) * 64 +
                                           ((ks * 4 + quad) ^ sw) * 8);
                accS[mt] = __builtin_amdgcn_mfma_f32_16x16x32_f16(af, qf[ks],
                                                                  accS[mt], 0, 0, 0);
            }
        }

        // ---- p = km * 2^s (exact 0 when masked); deferred l reduction ----
#pragma unroll
        for (int mt = 0; mt < 4; ++mt) {
            float kmr[4] = {kmv[mt].x, kmv[mt].y, kmv[mt].z, kmv[mt].w};
            half4 p4;
#pragma unroll
            for (int r = 0; r < 4; ++r) {
                float p = kmr[r] * __builtin_amdgcn_exp2f(accS[mt][r]);
                l_i += p;
                p4[r] = (half_t)p;
            }
            int cw = mt * 2 + (quad >> 1);
            *(half4*)(Psw + l15 * 64 + ((cw ^ sw) * 8 + (quad & 1) * 4)) = p4;
        }

        // ---- O += P V  (per-wave P: same-wave lgkmcnt ordering suffices) ----
#pragma unroll
        for (int ks2 = 0; ks2 < 2; ++ks2) {
            const int ko = ((ks2 * 4 + quad) ^ sw) * 8;
            half8 pf = *(const half8*)(Psw + l15 * 64 + ko);
#pragma unroll
            for (int nt = 0; nt < 4; ++nt) {
                half8 vf = *(const half8*)(Vs[buf] + (nt * 16 + l15) * 64 + ko);
                accO[nt] = __builtin_amdgcn_mfma_f32_16x16x32_f16(pf, vf,
                                                                  accO[nt], 0, 0, 0);
            }
        }
    }

    // final l reduction across quads (disjoint key subsets per quad)
    l_i += __shfl_xor(l_i, 16, 64);
    l_i += __shfl_xor(l_i, 32, 64);
    const float linv = (qm > 0.5f && l_i > 0.f) ? 1.0f / l_i : 0.f;
    float inv[4];
#pragma unroll
    for (int r = 0; r < 4; ++r) inv[r] = __shfl(linv, quad * 4 + r, 64);
#pragma unroll
    for (int nt = 0; nt < 4; ++nt)
#pragma unroll
        for (int r = 0; r < 4; ++r) {
            size_t row = (size_t)(b * SEQ + qi0 + wave * 16 + quad * 4 + r);
            aout[row * INNER + h * DH + nt * 16 + l15] = (half_t)(accO[nt][r] * inv[r]);
        }
}

// ------------------------------- launch ------------------------------------
extern "C" void kernel_launch(void* const* d_in, const int* in_sizes, int n_in,
                              void* d_out, int out_size, void* d_ws, size_t ws_size,
                              hipStream_t stream) {
    const float* x    = (const float*)d_in[0];
    const float* mask = (const float*)d_in[1];
    const float* Wqkv = (const float*)d_in[2];   // [1024][3072]
    const float* Wout = (const float*)d_in[3];   // [1024][1024]
    float* out = (float*)d_out;

    half_t* x_h    = (half_t*)d_ws;                       // 4  Mi halves
    half_t* Wqkv_t = x_h + (size_t)4 * 1024 * 1024;       // 3  Mi  [3072][1024]
    half_t* Wout_t = Wqkv_t + (size_t)3 * 1024 * 1024;    // 1  Mi  [1024][1024]
    half_t* qkv_h  = Wout_t + (size_t)1024 * 1024;        // 12 Mi  [4096][3072]
    half_t* aout_h = qkv_h + (size_t)12 * 1024 * 1024;    // 4  Mi  [4096][1024]
    half_t* vt     = aout_h + (size_t)4 * 1024 * 1024;    // 4  Mi  [32][64][2048]

    prep<<<6144, 256, 0, stream>>>(x, Wqkv, Wout, x_h, Wqkv_t, Wout_t);

    gemm_f16_bt<1><<<dim3(3 * INNER / GBN, BROWS / GBM), 256, 0, stream>>>(
        x_h, Wqkv_t, qkv_h, BROWS, 3 * INNER, DIM);

    vtrans<<<dim3(SEQ / 32, 2 * NH), 256, 0, stream>>>(qkv_h, vt);

    attn_mfma<<<dim3(SEQ / 64, 2 * NH), 256, 0, stream>>>(qkv_h, vt, mask, aout_h);

    gemm_f16_bt<0><<<dim3(DIM / GBN, BROWS / GBM), 256, 0, stream>>>(
        aout_h, Wout_t, out, BROWS, DIM, INNER);
}

// Round 7
// 198.234 us; speedup vs baseline: 1.1175x; 1.0400x over previous
//
#include <hip/hip_runtime.h>

// ---------------------------------------------------------------------------
// Attention_25151328485403 — f16 MFMA path, round 7
//   prep: fused converts (x->f16; W_qkv -> [N][K] q-cols ×0.125*log2e; W_out)
//   g1 :  qkv_h = x_h @ Wqkv^T; V-blocks (n0>=2048) written TRANSPOSED to vt
//   at :  flash attn, round-4 structure (single buffer, 2 barriers/tile) +
//         whole mask row LDS-resident (no vmcnt traffic in loop)
//   g2 :  out = aout_h @ Wout^T, 64x128 tile (512 blocks = 2/CU)
// Lessons: R5 — 32q/wave kills grid occupancy; R6 — per-tile global kmask
// loads defeat dbuf prefetch (vmcnt is in-order). Keep loop vmcnt-clean.
// ---------------------------------------------------------------------------

typedef _Float16 half_t;
typedef __attribute__((ext_vector_type(8))) _Float16 half8;
typedef __attribute__((ext_vector_type(4))) _Float16 half4;
typedef __attribute__((ext_vector_type(4))) float floatx4;

#define SEQ 2048
#define DIM 1024
#define INNER 1024
#define NH 16
#define DH 64
#define BROWS 4096

__device__ inline void async16(const half_t* g, half_t* l) {
    __builtin_amdgcn_global_load_lds(
        (const __attribute__((address_space(1))) void*)g,
        (__attribute__((address_space(3))) void*)l, 16, 0, 0);
}

// ------------------------- fused prep (all converts) -----------------------
__global__ __launch_bounds__(256) void prep(const float* __restrict__ x,
                                            const float* __restrict__ Wqkv,
                                            const float* __restrict__ Wout,
                                            half_t* __restrict__ x_h,
                                            half_t* __restrict__ Wqkv_t,
                                            half_t* __restrict__ Wout_t) {
    __shared__ float tile[32][33];
    const int bid = blockIdx.x;
    const int tid = threadIdx.x;

    if (bid < 2048) {
        int i = (bid * 256 + tid) * 8;
        float4 v0 = *(const float4*)(x + i);
        float4 v1 = *(const float4*)(x + i + 4);
        half_t h[8];
        h[0] = (half_t)v0.x; h[1] = (half_t)v0.y; h[2] = (half_t)v0.z; h[3] = (half_t)v0.w;
        h[4] = (half_t)v1.x; h[5] = (half_t)v1.y; h[6] = (half_t)v1.z; h[7] = (half_t)v1.w;
        *(half8*)(x_h + i) = *(half8*)h;
        return;
    }

    const float* in;
    half_t* out;
    int R, C, scaleRows, c0, r0;
    float scale;
    if (bid < 5120) {
        int idx = bid - 2048;                 // W_qkv: 96 x 32 tiles
        in = Wqkv; out = Wqkv_t; R = DIM; C = 3 * INNER;
        scaleRows = INNER; scale = 0.1803368801111f;   // 0.125 * log2(e)
        c0 = (idx % 96) * 32; r0 = (idx / 96) * 32;
    } else {
        int idx = bid - 5120;                 // W_out: 32 x 32 tiles
        in = Wout; out = Wout_t; R = INNER; C = DIM;
        scaleRows = 0; scale = 1.0f;
        c0 = (idx % 32) * 32; r0 = (idx / 32) * 32;
    }
    const int tx = tid & 31, ty = tid >> 5;
#pragma unroll
    for (int i = 0; i < 32; i += 8)
        tile[ty + i][tx] = in[(size_t)(r0 + ty + i) * C + c0 + tx];
    __syncthreads();
#pragma unroll
    for (int i = 0; i < 32; i += 8) {
        int oc = c0 + ty + i;
        float s = (oc < scaleRows) ? scale : 1.0f;
        out[(size_t)oc * R + r0 + tx] = (half_t)(tile[tx][ty + i] * s);
    }
}

// ------------------------------ mfma GEMM ----------------------------------
// C[M,N] = A[M,K] * B^T (B stored [N][K]).  Block = 2x2 waves, wave tile =
// (WMT*16) x (WNT*16).  VTOUT: blocks with n0>=2048 write transposed into vt
// ([bh][64 d][2048 seq]) instead of Cout (V-part consumed only via vt).
template <int OUTF16, int WMT, int WNT, int VTOUT>
__global__ __launch_bounds__(256) void gemm_f16_bt(const half_t* __restrict__ A,
                                                   const half_t* __restrict__ B,
                                                   void* __restrict__ Cout,
                                                   half_t* __restrict__ vt,
                                                   int M, int N, int K) {
    constexpr int BM = 32 * WMT;
    constexpr int BN = 32 * WNT;
    __shared__ half_t As[BM * 64];
    __shared__ half_t Bs[BN * 64];
    const int tid = threadIdx.x;
    const int wave = tid >> 6;
    const int lane = tid & 63;
    const int l15 = lane & 15;
    const int quad = lane >> 4;
    const int m0 = blockIdx.y * BM;
    const int n0 = blockIdx.x * BN;
    const int wm = (wave & 1) * (16 * WMT);
    const int wn = (wave >> 1) * (16 * WNT);

    floatx4 acc[WMT][WNT];
#pragma unroll
    for (int i = 0; i < WMT; ++i)
#pragma unroll
        for (int j = 0; j < WNT; ++j) acc[i][j] = (floatx4){0.f, 0.f, 0.f, 0.f};

    for (int k0 = 0; k0 < K; k0 += 64) {
        __syncthreads();
#pragma unroll
        for (int i = 0; i < BM * 8 / 256; ++i) {
            int chunk = i * 256 + tid;
            int row = chunk >> 3, c = chunk & 7;
            int gc = c ^ (row & 7);
            async16(A + (size_t)(m0 + row) * K + k0 + gc * 8, As + chunk * 8);
        }
#pragma unroll
        for (int i = 0; i < BN * 8 / 256; ++i) {
            int chunk = i * 256 + tid;
            int row = chunk >> 3, c = chunk & 7;
            int gc = c ^ (row & 7);
            async16(B + (size_t)(n0 + row) * K + k0 + gc * 8, Bs + chunk * 8);
        }
        __syncthreads();
#pragma unroll
        for (int ks = 0; ks < 2; ++ks) {
            const int g = ks * 4 + quad;
            half8 af[WMT], bf[WNT];
#pragma unroll
            for (int i = 0; i < WMT; ++i) {
                int m = wm + i * 16 + l15;
                af[i] = *(const half8*)(As + m * 64 + (g ^ (m & 7)) * 8);
            }
#pragma unroll
            for (int j = 0; j < WNT; ++j) {
                int n = wn + j * 16 + l15;
                bf[j] = *(const half8*)(Bs + n * 64 + (g ^ (n & 7)) * 8);
            }
#pragma unroll
            for (int i = 0; i < WMT; ++i)
#pragma unroll
                for (int j = 0; j < WNT; ++j)
                    acc[i][j] = __builtin_amdgcn_mfma_f32_16x16x32_f16(af[i], bf[j],
                                                                       acc[i][j], 0, 0, 0);
        }
    }

    if (VTOUT && n0 >= 2 * INNER) {
        // V block: write transposed to vt[bh][d][seq] as half4 along seq
#pragma unroll
        for (int i = 0; i < WMT; ++i) {
            int row0 = m0 + wm + i * 16 + quad * 4;
            int seq0 = row0 & (SEQ - 1);
            int bhb = (row0 >> 11) << 4;           // b * 16
#pragma unroll
            for (int j = 0; j < WNT; ++j) {
                int vc = n0 + wn + j * 16 + l15 - 2 * INNER;   // h*64 + d
                half4 v4;
#pragma unroll
                for (int r = 0; r < 4; ++r) v4[r] = (half_t)acc[i][j][r];
                *(half4*)(vt + ((size_t)(bhb + (vc >> 6)) * DH + (vc & 63)) * SEQ +
                          seq0) = v4;
            }
        }
        return;
    }

#pragma unroll
    for (int i = 0; i < WMT; ++i)
#pragma unroll
        for (int j = 0; j < WNT; ++j)
#pragma unroll
            for (int r = 0; r < 4; ++r) {
                size_t row = m0 + wm + i * 16 + quad * 4 + r;
                size_t col = n0 + wn + j * 16 + l15;
                if (OUTF16)
                    ((half_t*)Cout)[row * N + col] = (half_t)acc[i][j][r];
                else
                    ((float*)Cout)[row * N + col] = acc[i][j][r];
            }
}

// ------------------------------ attention ----------------------------------
// 256 thr = 4 waves; 64 queries/block (16/wave); K-tiles of 64, single buffer,
// 2 barriers/tile (round-4 structure). Whole mask row LDS-resident -> loop is
// vmcnt-clean except staging. S^T = K·Q^T (lane's 16 scores share q = l15).
// No running max: scores sd~1, fp32 exp2 + half-P have >10 sigma headroom.
__global__ __launch_bounds__(256) void attn_mfma(const half_t* __restrict__ qkv,
                                                 const half_t* __restrict__ vt,
                                                 const float* __restrict__ mask,
                                                 half_t* __restrict__ aout) {
    __shared__ half_t Ks[64 * 64];        // [key][d], chunks xor-swizzled
    __shared__ half_t Vs[64 * 64];        // [d][key], chunks xor-swizzled
    __shared__ half_t Ps[4][16 * 64];     // per-wave [q][key], chunks xor-swizzled
    __shared__ float smask[SEQ];          // whole mask row for this b

    const int tid = threadIdx.x;
    const int wave = tid >> 6;
    const int lane = tid & 63;
    const int l15 = lane & 15;
    const int quad = lane >> 4;
    const int sw = l15 & 7;               // xor swizzle key for rows ≡ l15 (mod 8)
    const int bh = blockIdx.y;
    const int b = bh >> 4, h = bh & 15;
    const int qi0 = blockIdx.x * 64;

    // stage entire mask row once (512 float4 over 256 threads)
    {
        const float4* msrc = (const float4*)(mask + (size_t)b * SEQ);
        ((float4*)smask)[tid] = msrc[tid];
        ((float4*)smask)[256 + tid] = msrc[256 + tid];
    }

    // Q fragments direct from global (log2e*0.125 folded into W_qkv q-cols)
    const half_t* qrow = qkv + (size_t)(b * SEQ + qi0 + wave * 16 + l15) * 3072 + h * DH;
    half8 qf[2];
    qf[0] = *(const half8*)(qrow + quad * 8);
    qf[1] = *(const half8*)(qrow + 32 + quad * 8);
    const float qm = mask[(size_t)b * SEQ + qi0 + wave * 16 + l15];

    const half_t* kbase0 = qkv + (size_t)b * SEQ * 3072 + INNER + h * DH;
    const half_t* vtb = vt + (size_t)bh * DH * SEQ;
    half_t* Psw = &Ps[wave][0];

    floatx4 accO[4];
#pragma unroll
    for (int nt = 0; nt < 4; ++nt) accO[nt] = (floatx4){0.f, 0.f, 0.f, 0.f};
    float l_i = 0.f;    // per-lane partial: keys {mt*16+quad*4+r}, q = l15

    for (int kt = 0; kt < SEQ / 64; ++kt) {
        const int kj0 = kt * 64;
        __syncthreads();                  // prior tile's reads done (iter0: smask)
#pragma unroll
        for (int i = 0; i < 2; ++i) {
            int chunk = i * 256 + tid;
            int row = chunk >> 3, c = chunk & 7;
            int gc = c ^ (row & 7);
            async16(kbase0 + (size_t)(kj0 + row) * 3072 + gc * 8, Ks + chunk * 8);
        }
#pragma unroll
        for (int i = 0; i < 2; ++i) {
            int chunk = i * 256 + tid;
            int row = chunk >> 3, c = chunk & 7;
            int gc = c ^ (row & 7);
            async16(vtb + (size_t)row * SEQ + kj0 + gc * 8, Vs + chunk * 8);
        }
        __syncthreads();                  // staging landed (vmcnt+lgkm drain)

        // key masks from LDS-resident row (quad-uniform b128 broadcast)
        float4 kmv[4];
#pragma unroll
        for (int mt = 0; mt < 4; ++mt)
            kmv[mt] = *(const float4*)&smask[kj0 + mt * 16 + quad * 4];

        // ---- S^T = K Q^T : rows = keys (mt*16+quad*4+r), cols = q (l15) ----
        floatx4 accS[4];
#pragma unroll
        for (int mt = 0; mt < 4; ++mt) accS[mt] = (floatx4){0.f, 0.f, 0.f, 0.f};
#pragma unroll
        for (int ks = 0; ks < 2; ++ks) {
#pragma unroll
            for (int mt = 0; mt < 4; ++mt) {
                half8 af = *(const half8*)(Ks + (mt * 16 + l15) * 64 +
                                           ((ks * 4 + quad) ^ sw) * 8);
                accS[mt] = __builtin_amdgcn_mfma_f32_16x16x32_f16(af, qf[ks],
                                                                  accS[mt], 0, 0, 0);
            }
        }

        // ---- p = km * 2^s (exact 0 when masked); deferred l reduction ----
#pragma unroll
        for (int mt = 0; mt < 4; ++mt) {
            float kmr[4] = {kmv[mt].x, kmv[mt].y, kmv[mt].z, kmv[mt].w};
            half4 p4;
#pragma unroll
            for (int r = 0; r < 4; ++r) {
                float p = kmr[r] * __builtin_amdgcn_exp2f(accS[mt][r]);
                l_i += p;
                p4[r] = (half_t)p;
            }
            int cw = mt * 2 + (quad >> 1);
            *(half4*)(Psw + l15 * 64 + ((cw ^ sw) * 8 + (quad & 1) * 4)) = p4;
        }

        // ---- O += P V  (per-wave P: same-wave lgkmcnt ordering suffices) ----
#pragma unroll
        for (int ks2 = 0; ks2 < 2; ++ks2) {
            const int ko = ((ks2 * 4 + quad) ^ sw) * 8;
            half8 pf = *(const half8*)(Psw + l15 * 64 + ko);
#pragma unroll
            for (int nt = 0; nt < 4; ++nt) {
                half8 vf = *(const half8*)(Vs + (nt * 16 + l15) * 64 + ko);
                accO[nt] = __builtin_amdgcn_mfma_f32_16x16x32_f16(pf, vf,
                                                                  accO[nt], 0, 0, 0);
            }
        }
    }

    // final l reduction across quads (disjoint key subsets per quad)
    l_i += __shfl_xor(l_i, 16, 64);
    l_i += __shfl_xor(l_i, 32, 64);
    const float linv = (qm > 0.5f && l_i > 0.f) ? 1.0f / l_i : 0.f;
    float inv[4];
#pragma unroll
    for (int r = 0; r < 4; ++r) inv[r] = __shfl(linv, quad * 4 + r, 64);
#pragma unroll
    for (int nt = 0; nt < 4; ++nt)
#pragma unroll
        for (int r = 0; r < 4; ++r) {
            size_t row = (size_t)(b * SEQ + qi0 + wave * 16 + quad * 4 + r);
            aout[row * INNER + h * DH + nt * 16 + l15] = (half_t)(accO[nt][r] * inv[r]);
        }
}

// ------------------------------- launch ------------------------------------
extern "C" void kernel_launch(void* const* d_in, const int* in_sizes, int n_in,
                              void* d_out, int out_size, void* d_ws, size_t ws_size,
                              hipStream_t stream) {
    const float* x    = (const float*)d_in[0];
    const float* mask = (const float*)d_in[1];
    const float* Wqkv = (const float*)d_in[2];   // [1024][3072]
    const float* Wout = (const float*)d_in[3];   // [1024][1024]
    float* out = (float*)d_out;

    half_t* x_h    = (half_t*)d_ws;                       // 4  Mi halves
    half_t* Wqkv_t = x_h + (size_t)4 * 1024 * 1024;       // 3  Mi  [3072][1024]
    half_t* Wout_t = Wqkv_t + (size_t)3 * 1024 * 1024;    // 1  Mi  [1024][1024]
    half_t* qkv_h  = Wout_t + (size_t)1024 * 1024;        // 12 Mi  [4096][3072]
    half_t* aout_h = qkv_h + (size_t)12 * 1024 * 1024;    // 4  Mi  [4096][1024]
    half_t* vt     = aout_h + (size_t)4 * 1024 * 1024;    // 4  Mi  [32][64][2048]

    prep<<<6144, 256, 0, stream>>>(x, Wqkv, Wout, x_h, Wqkv_t, Wout_t);

    // qkv projection; V-blocks written transposed straight into vt
    gemm_f16_bt<1, 4, 4, 1><<<dim3(3 * INNER / 128, BROWS / 128), 256, 0, stream>>>(
        x_h, Wqkv_t, qkv_h, vt, BROWS, 3 * INNER, DIM);

    attn_mfma<<<dim3(SEQ / 64, 2 * NH), 256, 0, stream>>>(qkv_h, vt, mask, aout_h);

    // output projection, 64x128 tile -> 512 blocks (2/CU)
    gemm_f16_bt<0, 2, 4, 0><<<dim3(DIM / 128, BROWS / 64), 256, 0, stream>>>(
        aout_h, Wout_t, out, nullptr, BROWS, DIM, INNER);
}